// Round 13
// baseline (364.175 us; speedup 1.0000x reference)
//
#include <hip/hip_runtime.h>

#define BB 4
#define CC 64
#define HH 128
#define WW 128
#define NN (HH*WW)      // 16384
#define HP 130
#define NPP (HP*HP)     // 16900 (1-pad field: r)
#define HPS 136
#define VROWS 132
#define NPPS (VROWS*HPS) // 17952 (K/V fields: 2-row pad, 4-col left pad, 136-stride)
#define HP2 132
#define NPP2 (HP2*HP2)  // 17424 (2-pad field: Q)
#define NH 8
#define DD 72

// ---------------- KZ: zero only the pad rings (replaces 57 MB memset) -----------------
__global__ __launch_bounds__(256) void kz_pads(float* __restrict__ Qp, float* __restrict__ Kp,
                                               float* __restrict__ rfp){
    const int t = threadIdx.x;
    const int c = blockIdx.x;      // 0..255 Q | 256..767 K,V | 768..799 r
    if (c < 256){
        float* f = Qp + (size_t)c*NPP2;
        for (int idx=t; idx<4*HP2; idx+=256){
            int rs = idx / HP2, col = idx - rs*HP2;
            int row = (rs<2)? rs : (128+rs);          // 0,1,130,131
            f[row*HP2 + col] = 0.f;
        }
        for (int idx=t; idx<128*4; idx+=256){
            int row = 2 + (idx>>2), cs = idx&3;
            int col = (cs<2)? cs : (128+cs);          // 0,1,130,131
            f[row*HP2 + col] = 0.f;
        }
    } else if (c < 768){
        float* f = Kp + (size_t)(c-256)*NPPS;         // K then V (contiguous)
        for (int idx=t; idx<4*HPS; idx+=256){
            int rs = idx / HPS, col = idx - rs*HPS;
            int row = (rs<2)? rs : (128+rs);          // 0,1,130,131
            f[row*HPS + col] = 0.f;
        }
        for (int idx=t; idx<128*8; idx+=256){
            int row = 2 + (idx>>3), cs = idx&7;
            int col = (cs<4)? cs : (128+cs);          // 0..3, 132..135
            f[row*HPS + col] = 0.f;
        }
    } else {
        float* f = rfp + (size_t)(c-768)*NPP;
        for (int idx=t; idx<2*HP; idx+=256){
            int rs = idx / HP, col = idx - rs*HP;
            f[(rs?129:0)*HP + col] = 0.f;
        }
        for (int idx=t; idx<128*2; idx+=256){
            int row = 1 + (idx>>1);
            f[row*HP + ((idx&1)?129:0)] = 0.f;
        }
    }
}

// ---------------- K0: transpose w_proj -> wt[ci][w][oc]; w_qkv -> wqkvT[gy][c][orel] --
__global__ __launch_bounds__(256) void k0_wt(const float* __restrict__ wproj,
                                             const float* __restrict__ wqkv,
                                             float* __restrict__ wt, float* __restrict__ wqkvT){
    int idx = blockIdx.x*256 + threadIdx.x;      // 36864 + 12288 = 49152
    if (idx < 64*9*64){
        int oc = idx & 63;
        int w  = (idx >> 6) % 9;
        int ci = idx / 576;
        wt[idx] = wproj[(oc*64 + ci)*9 + w];
    } else if (idx < 64*9*64 + 3*64*64){
        int i2 = idx - 64*9*64;
        int orel = i2 & 63, c = (i2 >> 6) & 63, gy = i2 >> 12;
        wqkvT[i2] = wqkv[(gy*64 + orel)*64 + c];
    }
}

// ---------------- K1: qkv = x @ w_qkv^T + b ; weights via wave-uniform scalar loads ---
__global__ __launch_bounds__(256) void k1_qkv(const float* __restrict__ x,
        const float* __restrict__ wqkvT, const float* __restrict__ bqkv,
        float* __restrict__ Qp, float* __restrict__ Kp, float* __restrict__ Vp){
    const int t = threadIdx.x;
    const int gy = blockIdx.y;    // 0=q,1=k,2=v
    const int b  = blockIdx.z;
    const int pix = blockIdx.x*256 + t;
    float acc[64];
#pragma unroll
    for (int o=0;o<64;++o) acc[o]=0.f;
    const float* xb = x + (size_t)(b*64)*NN + pix;
    const float* wT = wqkvT + gy*4096;           // [c][orel], uniform addresses
    for (int c=0;c<64;++c){
        float xv = xb[(size_t)c*NN];
        const float4* wr = (const float4*)(wT + c*64);
#pragma unroll
        for (int o4=0;o4<16;++o4){
            float4 wv = wr[o4];                  // uniform -> s_load, SGPR operands
            acc[o4*4+0] += xv*wv.x;
            acc[o4*4+1] += xv*wv.y;
            acc[o4*4+2] += xv*wv.z;
            acc[o4*4+3] += xv*wv.w;
        }
    }
    const int y = pix >> 7, xx = pix & 127;
    float* dst; size_t cstride;
    if (gy == 0){ dst = Qp + (size_t)(b*64)*NPP2 + (y+2)*HP2 + (xx+2); cstride = NPP2; }
    else { dst = ((gy==1)?Kp:Vp) + (size_t)(b*64)*NPPS + (y+2)*HPS + (xx+4); cstride = NPPS; }
    const bool dorelu = (gy < 2);
    const float* bl = bqkv + gy*64;              // uniform -> scalar
#pragma unroll
    for (int o=0;o<64;++o){
        float v = acc[o] + bl[o];
        if (dorelu) v = fmaxf(v, 0.f);
        dst[(size_t)o*cstride] = v;
    }
}

// ---------------- K2: ksum[b][h][cl*9+w] = windowed sums of Kpad ----------------------
__global__ __launch_bounds__(256) void k2_ksum(const float* __restrict__ Kp, float* __restrict__ ksum){
    const int c = blockIdx.x, b = blockIdx.y;
    const float* src = Kp + (size_t)(b*64 + c)*NPPS;
    float a[3][3];
#pragma unroll
    for (int i=0;i<3;++i)
#pragma unroll
        for (int j=0;j<3;++j) a[i][j]=0.f;
    for (int idx = threadIdx.x; idx < NPPS; idx += 256){
        int r = idx / HPS, cc = idx - r*HPS;
        float v = src[idx];
#pragma unroll
        for (int i=0;i<3;++i){
            bool fy = (unsigned)(r - 1 - i) < 128u;
#pragma unroll
            for (int j=0;j<3;++j){
                bool fx = (unsigned)(cc - 3 - j) < 128u;
                if (fy && fx) a[i][j] += v;
            }
        }
    }
    __shared__ float red[4][9];
#pragma unroll
    for (int i=0;i<3;++i)
#pragma unroll
        for (int j=0;j<3;++j){
            float v = a[i][j];
            for (int m=1;m<64;m<<=1) v += __shfl_xor(v, m, 64);
            a[i][j] = v;
        }
    int wave = threadIdx.x >> 6, lane = threadIdx.x & 63;
    if (lane == 0){
#pragma unroll
        for (int w=0;w<9;++w) red[wave][w] = a[w/3][w%3];
    }
    __syncthreads();
    if (threadIdx.x < 9){
        float s = red[0][threadIdx.x]+red[1][threadIdx.x]+red[2][threadIdx.x]+red[3][threadIdx.x];
        int h = c >> 3, cl = c & 7;
        ksum[(b*NH + h)*DD + cl*9 + threadIdx.x] = s;
    }
}

// ---------------- K3a: 5x5 cross-correlation, rolling V-row register window -----------
__global__ __launch_bounds__(256) void k3a_corr(const float* __restrict__ Kp, const float* __restrict__ Vp,
                                                float* __restrict__ Cpart){
    const int t = threadIdx.x;
    const int pair = blockIdx.x;      // cd*8+ce
    const int cd = pair >> 3, ce = pair & 7;
    const int h = blockIdx.y, b = blockIdx.z;
    const int bh = b*NH + h;
    const float* Kc = Kp + (size_t)(b*64 + h*8 + cd)*NPPS;
    const float* Vc = Vp + (size_t)(b*64 + h*8 + ce)*NPPS;
    const int x0 = (t & 31) * 4;      // image col group (4 px), contiguous across wave
    const int yb = t >> 5;            // row slice 0..7 (16 rows each)
    const int y0 = yb*16;
    float C[25];
#pragma unroll
    for (int k=0;k<25;++k) C[k]=0.f;

    float vv[5][12];                  // rolling window of padded V rows y0+it .. y0+it+4
    const float* vbase = Vc + (size_t)y0*HPS + x0;
#pragma unroll
    for (int rr=0; rr<4; ++rr){
#pragma unroll
        for (int q=0;q<3;++q){
            float4 a = *(const float4*)(vbase + rr*HPS + 4*q);
            vv[rr][4*q]=a.x; vv[rr][4*q+1]=a.y; vv[rr][4*q+2]=a.z; vv[rr][4*q+3]=a.w;
        }
    }
#pragma unroll
    for (int it=0; it<16; ++it){
        const int slot = (it+4)%5;    // static after unroll
#pragma unroll
        for (int q=0;q<3;++q){
            float4 a = *(const float4*)(vbase + (it+4)*HPS + 4*q);
            vv[slot][4*q]=a.x; vv[slot][4*q+1]=a.y; vv[slot][4*q+2]=a.z; vv[slot][4*q+3]=a.w;
        }
        float4 kk4 = *(const float4*)(Kc + (size_t)(y0+it+2)*HPS + 4 + x0);
        float kk[4] = {kk4.x, kk4.y, kk4.z, kk4.w};
#pragma unroll
        for (int dr=0; dr<5; ++dr){
            const float* vrow = vv[(it+dr)%5];
#pragma unroll
            for (int dj=0; dj<5; ++dj)
#pragma unroll
                for (int p=0; p<4; ++p)
                    C[dr*5+dj] += kk[p] * vrow[p+dj+2];
        }
    }
#pragma unroll
    for (int k=0;k<25;++k){
        float v = C[k];
        for (int m=1;m<64;m<<=1) v += __shfl_xor(v, m, 64);
        C[k] = v;
    }
    __shared__ float red[4][25];
    const int wave = t >> 6, lane = t & 63;
    if (lane == 0){
#pragma unroll
        for (int k=0;k<25;++k) red[wave][k] = C[k];
    }
    __syncthreads();
    if (t < 25){
        float s = red[0][t]+red[1][t]+red[2][t]+red[3][t];
        Cpart[((size_t)bh*64 + pair)*25 + t] = s;
    }
}

// ---------------- K3c: boundary corrections + assemble kvT2 --------------------------
__global__ __launch_bounds__(128) void k3c_kv(const float* __restrict__ Kp, const float* __restrict__ Vp,
                                              const float* __restrict__ Cpart, float* __restrict__ kvT2){
    __shared__ float Krow[2][136];   // K image rows 0 (side0) / 127 (side1)
    __shared__ float Vrow[10][136];  // V padded rows 0..4, 127..131
    __shared__ float Kcol[132][2];   // K padded cols 4 (side0) / 131 (side1), all rows
    __shared__ float Vcol[132][16];  // V padded cols 0..7, 128..135, all rows
    __shared__ float corr[100];      // [kind][side][di2][dj2]
    __shared__ float C25s[25];
    const int t = threadIdx.x;
    const int pair = blockIdx.x;
    const int cd = pair >> 3, ce = pair & 7;
    const int h = blockIdx.y, b = blockIdx.z;
    const int bh = b*NH + h;
    const float* Kc = Kp + (size_t)(b*64 + h*8 + cd)*NPPS;
    const float* Vc = Vp + (size_t)(b*64 + h*8 + ce)*NPPS;
    for (int idx=t; idx<2*136; idx+=128){
        int side = idx/136, col = idx - side*136;
        Krow[side][col] = Kc[(side?129:2)*HPS + col];
    }
    for (int idx=t; idx<10*136; idx+=128){
        int s = idx/136, col = idx - s*136;
        int row = (s<5)? s : (122+s);
        Vrow[s][col] = Vc[row*HPS + col];
    }
    for (int idx=t; idx<132*2; idx+=128){
        int row = idx>>1, side = idx&1;
        Kcol[row][side] = Kc[row*HPS + (side?131:4)];
    }
    for (int idx=t; idx<132*16; idx+=128){
        int row = idx>>4, g = idx&15;
        Vcol[row][g] = Vc[row*HPS + ((g<8)? g : (120+g))];
    }
    __syncthreads();
    if (t < 100){
        int kind = t/50, rem = t%50, side = rem/25, sh = rem%25;
        int di2 = sh/5, dj2 = sh - di2*5;
        float s = 0.f;
        if (kind == 0){
            const float* kr = &Krow[side][4];
            const float* vr = &Vrow[side*5+di2][2+dj2];
            for (int bb=0; bb<128; ++bb) s += kr[bb]*vr[bb];
        } else {
            const int g = side? (9+dj2) : (2+dj2);
            for (int a=0; a<128; ++a) s += Kcol[2+a][side]*Vcol[a+di2][g];
        }
        corr[t] = s;
    } else if (t < 125){
        C25s[t-100] = Cpart[((size_t)bh*64 + pair)*25 + (t-100)];
    }
    __syncthreads();
    if (t < 81){
        int i = t/27, j = (t/9)%3, i2 = (t/3)%3, j2 = t%3;
        int di2 = i2-i+2, dj2 = j2-j+2;
        float val = C25s[di2*5+dj2];
        int si = (i==0)?1:0;
        int sj = (j==0)?1:0;
        if (i != 1) val -= corr[si*25 + di2*5 + dj2];
        if (j != 1) val -= corr[50 + sj*25 + di2*5 + dj2];
        if (i != 1 && j != 1){
            int cj = (j==0)?127:0;
            val += Krow[si][4+cj] * Vrow[si*5+di2][2+cj+dj2];
        }
        kvT2[((size_t)bh*DD + ce*9 + i2*3 + j2)*96 + cd*12 + i*3 + j] = val;
    }
}

// ---------------- K4: r[b][h][pad(y,x)] = 1/(q . ksum + eps), zero-padded 130x130 -----
__global__ __launch_bounds__(256) void k4_r(const float* __restrict__ Qp, const float* __restrict__ ksum,
                                            float* __restrict__ rfp){
    const int h = blockIdx.y, b = blockIdx.z;
    __shared__ float ks[72];
    if (threadIdx.x < 72) ks[threadIdx.x] = ksum[(b*NH + h)*DD + threadIdx.x];
    __syncthreads();
    const int pix = blockIdx.x*256 + threadIdx.x;
    const int y = pix >> 7, xx = pix & 127;
    const float* Qb = Qp + (size_t)(b*64 + h*8)*NPP2 + (y+1)*HP2 + (xx+1);
    float denom = 0.f;
#pragma unroll
    for (int cl=0; cl<8; ++cl){
        const float* q = Qb + (size_t)cl*NPP2;
#pragma unroll
        for (int w=0; w<9; ++w){
            denom += q[(w/3)*HP2 + (w%3)] * ks[cl*9 + w];
        }
    }
    rfp[(size_t)(b*NH + h)*NPP + (y+1)*HP + (xx+1)] = 1.f/(denom + 1e-6f);
}

// ---------------- K5: fused numerator + fold + count-normalize ------------------------
__global__ __launch_bounds__(512) void k5_attn(const float* __restrict__ Qp, const float* __restrict__ kvT2,
          const float* __restrict__ rfp, float* __restrict__ folded){
    __shared__ __align__(16) float Qt[8*20*20];   // [cl][20 rows][20 cols], origin (ty0-2,tx0-2)
    __shared__ __align__(16) float rt[18*20];     // [18 rows][stride 20], origin (ty0-1,tx0-1)
    const int t = threadIdx.x;
    const int tile = blockIdx.x;    // 8x8 tiles of 16x16
    const int h = blockIdx.y, b = blockIdx.z;
    const int ty0 = (tile >> 3)*16, tx0 = (tile & 7)*16;

    const float* Qb = Qp + (size_t)(b*64 + h*8)*NPP2 + (size_t)ty0*HP2 + tx0;
    for (int idx=t; idx<8*20*20; idx+=512){
        int cl = idx / 400; int rem = idx - cl*400; int r = rem/20, cc = rem - r*20;
        Qt[idx] = Qb[(size_t)cl*NPP2 + r*HP2 + cc];
    }
    const float* rg = rfp + (size_t)(b*NH + h)*NPP + (size_t)ty0*HP + tx0;
    for (int idx=t; idx<18*18; idx+=512){
        int rr = idx / 18, cc = idx - rr*18;
        rt[rr*20 + cc] = rg[rr*HP + cc];
    }
    __syncthreads();

    const int c  = __builtin_amdgcn_readfirstlane(t >> 6);  // wave-uniform channel
    const int l  = t & 63;
    const int pr = l >> 2;          // pixel row 0..15
    const int pc = (l & 3) * 4;     // pixel col start 0,4,8,12

    const float* kvc = kvT2 + ((size_t)(b*NH + h)*DD + c*9)*96;  // rows u=0..8, stride 96

    float acc[9][4];
#pragma unroll
    for (int u=0;u<9;++u)
#pragma unroll
        for (int p=0;p<4;++p) acc[u][p]=0.f;

    for (int cl=0; cl<8; ++cl){
        float qw[5][8];
        const float* qb = &Qt[cl*400 + pr*20 + pc];
#pragma unroll
        for (int rr=0; rr<5; ++rr){
            float4 a0 = *(const float4*)(qb + rr*20);
            float4 a1 = *(const float4*)(qb + rr*20 + 4);
            qw[rr][0]=a0.x; qw[rr][1]=a0.y; qw[rr][2]=a0.z; qw[rr][3]=a0.w;
            qw[rr][4]=a1.x; qw[rr][5]=a1.y; qw[rr][6]=a1.z; qw[rr][7]=a1.w;
        }
#pragma unroll
        for (int u=0; u<9; ++u){
            const float* kr = kvc + u*96 + cl*12;   // wave-uniform address
            float kw[9];
#pragma unroll
            for (int i=0;i<9;++i) kw[i] = kr[i];
            const int iu = u/3, ju = u - iu*3;
#pragma unroll
            for (int w=0; w<9; ++w){
                const int rr = (w/3) - iu + 2;
                const int cc = (w%3) - ju + 2;
#pragma unroll
                for (int p=0;p<4;++p)
                    acc[u][p] += qw[rr][cc+p] * kw[w];
            }
        }
    }
    float rw[3][6];
    const float* rb = &rt[pr*20 + pc];
#pragma unroll
    for (int rr=0; rr<3; ++rr)
#pragma unroll
        for (int j=0; j<6; ++j) rw[rr][j] = rb[rr*20 + j];
    float out[4];
#pragma unroll
    for (int p=0;p<4;++p) out[p]=0.f;
#pragma unroll
    for (int u=0; u<9; ++u){
        const int iu = u/3, ju = u - iu*3;
#pragma unroll
        for (int p=0;p<4;++p)
            out[p] += acc[u][p] * rw[2-iu][p+2-ju];
    }
    // count-normalize here (moves k6's per-element divide out of its hot loop)
    const int iy = ty0 + pr;
    const float ry = 3.f - (float)(iy==0) - (float)(iy==127);
#pragma unroll
    for (int p=0;p<4;++p){
        const int ix = tx0 + pc + p;
        const float rx = 3.f - (float)(ix==0) - (float)(ix==127);
        out[p] = out[p] / (ry*rx);
    }
    float4 o4 = make_float4(out[0], out[1], out[2], out[3]);
    *(float4*)(&folded[(size_t)(b*64 + h*8 + c)*NN + (ty0+pr)*WW + tx0 + pc]) = o4;
}

// ---------------- K6: y = conv3x3(folded_norm, w_proj) + b_proj -----------------------
// 8x8 tiles (grid 1024), wave-uniform oc group (weights on SMEM pipe), ci-innermost
// LDS layout [tap][ci] (stride 68) -> ds_read_b128 covers 4 ci per read (144 vs 576).
__global__ __launch_bounds__(256) void k6_conv(const float* __restrict__ folded, const float* __restrict__ wt,
         const float* __restrict__ bproj, float* __restrict__ out){
    __shared__ __align__(16) float ut[120*68];   // [tap=rr*12+cc][ci], 32640 B
    const int t = threadIdx.x;
    const int tile = blockIdx.x;    // 0..255 : 16x16 grid of 8x8 tiles
    const int b = blockIdx.y;
    const int ty0 = (tile >> 4)*8, tx0 = (tile & 15)*8;

    // stage all 64 channels with halo, transposed to ci-innermost
    for (int idx=t; idx<6400; idx+=256){
        int ci = idx / 100; int rem = idx - ci*100; int rr = rem/10, cc = rem - rr*10;
        int iy = ty0 - 1 + rr, ix = tx0 - 1 + cc;
        float v = 0.f;
        if ((unsigned)iy < 128u && (unsigned)ix < 128u)
            v = folded[(size_t)(b*64 + ci)*NN + iy*WW + ix];
        ut[(rr*12 + cc)*68 + ci] = v;
    }
    __syncthreads();

    const int wv4 = __builtin_amdgcn_readfirstlane(t >> 6);  // wave-uniform oc group
    const int ocb = wv4*16;                                  // oc base: 0,16,32,48
    const int l  = t & 63;
    const int pr = l >> 3, pc = l & 7;                       // pixel in 8x8 tile

    float acc[16];
#pragma unroll
    for (int o=0;o<16;++o) acc[o]=0.f;

    const int tbase = pr*12 + pc;
    const float* wb  = wt + ocb;                             // wave-uniform
    for (int cg=0; cg<16; ++cg){                             // ci groups of 4
        float4 u4[9];
#pragma unroll
        for (int dy=0;dy<3;++dy)
#pragma unroll
            for (int dx=0;dx<3;++dx)
                u4[dy*3+dx] = *(const float4*)&ut[(tbase + dy*12 + dx)*68 + cg*4];
#pragma unroll
        for (int k=0;k<4;++k){
            const int ci = cg*4 + k;
#pragma unroll
            for (int w=0;w<9;++w){
                const float uv = (k==0)?u4[w].x:(k==1)?u4[w].y:(k==2)?u4[w].z:u4[w].w;
                const float* kr = wb + (ci*9 + w)*64;        // wave-uniform -> s_load
#pragma unroll
                for (int o=0;o<16;++o) acc[o] += kr[o]*uv;
            }
        }
    }
    const int y = ty0 + pr, x = tx0 + pc;
    const float* bb = bproj + ocb;                           // wave-uniform
    float* dst = &out[(size_t)(b*64 + ocb)*NN + y*WW + x];
#pragma unroll
    for (int o=0;o<16;++o) dst[(size_t)o*NN] = acc[o] + bb[o];
}

extern "C" void kernel_launch(void* const* d_in, const int* in_sizes, int n_in,
                              void* d_out, int out_size, void* d_ws, size_t ws_size,
                              hipStream_t stream) {
    const float* x     = (const float*)d_in[0];
    const float* wqkv  = (const float*)d_in[1];
    const float* bqkv  = (const float*)d_in[2];
    const float* wproj = (const float*)d_in[3];
    const float* bproj = (const float*)d_in[4];
    float* out = (float*)d_out;
    float* ws  = (float*)d_ws;

    const size_t szQ2 = (size_t)BB*CC*NPP2;      // 4,460,544 floats (2-pad Q)
    const size_t szFS = (size_t)BB*CC*NPPS;      // 4,595,712 floats (132x136 K/V)
    const size_t szR  = (size_t)BB*NH*NPP;       // 540,800 floats (1-pad r)
    const size_t szKV = (size_t)BB*NH*DD*96;     // 221,184 floats (kvT2)
    const size_t szKS = (size_t)BB*NH*DD;        // 2,304 floats (ksum)
    float* Qp2    = ws;
    float* Kp     = Qp2 + szQ2;
    float* Vp     = Kp + szFS;
    float* rfp    = Vp + szFS;
    float* kvT2   = rfp + szR;
    float* ksum   = kvT2 + szKV;
    float* folded = ksum + szKS;                 // B*C*N, also aliased as Cpart (k3a->k3c,
    float* wt     = folded + (size_t)BB*CC*NN;   //   consumed before k5 overwrites)
    float* wqkvT  = wt + (size_t)64*9*64;        // 3*64*64 = 12,288 floats
    float* Cpart  = folded;                      // 4*8*64*25 = 51,200 floats <= folded
    // total ~18.67M floats = ~74.7 MB of ws

    kz_pads <<<dim3(800),      256, 0, stream>>>(Qp2, Kp, rfp);
    k0_wt   <<<dim3(192),      256, 0, stream>>>(wproj, wqkv, wt, wqkvT);
    k1_qkv  <<<dim3(64, 3, 4), 256, 0, stream>>>(x, wqkvT, bqkv, Qp2, Kp, Vp);
    k2_ksum <<<dim3(64, 4),    256, 0, stream>>>(Kp, ksum);
    k3a_corr<<<dim3(64, 8, 4), 256, 0, stream>>>(Kp, Vp, Cpart);
    k3c_kv  <<<dim3(64, 8, 4), 128, 0, stream>>>(Kp, Vp, Cpart, kvT2);
    k4_r    <<<dim3(64, 8, 4), 256, 0, stream>>>(Qp2, ksum, rfp);
    k5_attn <<<dim3(64, 8, 4), 512, 0, stream>>>(Qp2, kvT2, rfp, folded);
    k6_conv <<<dim3(256, 4),   256, 0, stream>>>(folded, wt, bproj, out);
}

// Round 14
// 344.245 us; speedup vs baseline: 1.0579x; 1.0579x over previous
//
#include <hip/hip_runtime.h>

#define BB 4
#define CC 64
#define HH 128
#define WW 128
#define NN (HH*WW)      // 16384
#define HPS 136
#define VROWS 132
#define NPPS (VROWS*HPS) // 17952 (K/V fields: 2-row pad, 4-col left pad, 136-stride)
#define HP2 132
#define NPP2 (HP2*HP2)  // 17424 (2-pad field: Q)
#define NH 8
#define DD 72

// ---------------- KZ: zero only the pad rings ----------------------------------------
__global__ __launch_bounds__(256) void kz_pads(float* __restrict__ Qp, float* __restrict__ Kp){
    const int t = threadIdx.x;
    const int c = blockIdx.x;      // 0..255 Q | 256..767 K,V
    if (c < 256){
        float* f = Qp + (size_t)c*NPP2;
        for (int idx=t; idx<4*HP2; idx+=256){
            int rs = idx / HP2, col = idx - rs*HP2;
            int row = (rs<2)? rs : (128+rs);          // 0,1,130,131
            f[row*HP2 + col] = 0.f;
        }
        for (int idx=t; idx<128*4; idx+=256){
            int row = 2 + (idx>>2), cs = idx&3;
            int col = (cs<2)? cs : (128+cs);          // 0,1,130,131
            f[row*HP2 + col] = 0.f;
        }
    } else {
        float* f = Kp + (size_t)(c-256)*NPPS;         // K then V (contiguous)
        for (int idx=t; idx<4*HPS; idx+=256){
            int rs = idx / HPS, col = idx - rs*HPS;
            int row = (rs<2)? rs : (128+rs);          // 0,1,130,131
            f[row*HPS + col] = 0.f;
        }
        for (int idx=t; idx<128*8; idx+=256){
            int row = 2 + (idx>>3), cs = idx&7;
            int col = (cs<4)? cs : (128+cs);          // 0..3, 132..135
            f[row*HPS + col] = 0.f;
        }
    }
}

// ---------------- K0: transpose w_proj -> wt[ci][w][oc]; w_qkv -> wqkvT[gy][c][orel] --
__global__ __launch_bounds__(256) void k0_wt(const float* __restrict__ wproj,
                                             const float* __restrict__ wqkv,
                                             float* __restrict__ wt, float* __restrict__ wqkvT){
    int idx = blockIdx.x*256 + threadIdx.x;      // 36864 + 12288 = 49152
    if (idx < 64*9*64){
        int oc = idx & 63;
        int w  = (idx >> 6) % 9;
        int ci = idx / 576;
        wt[idx] = wproj[(oc*64 + ci)*9 + w];
    } else if (idx < 64*9*64 + 3*64*64){
        int i2 = idx - 64*9*64;
        int orel = i2 & 63, c = (i2 >> 6) & 63, gy = i2 >> 12;
        wqkvT[i2] = wqkv[(gy*64 + orel)*64 + c];
    }
}

// ---------------- K1: qkv = x @ w_qkv^T + b ; weights via wave-uniform scalar loads ---
__global__ __launch_bounds__(256) void k1_qkv(const float* __restrict__ x,
        const float* __restrict__ wqkvT, const float* __restrict__ bqkv,
        float* __restrict__ Qp, float* __restrict__ Kp, float* __restrict__ Vp){
    const int t = threadIdx.x;
    const int gy = blockIdx.y;    // 0=q,1=k,2=v
    const int b  = blockIdx.z;
    const int pix = blockIdx.x*256 + t;
    float acc[64];
#pragma unroll
    for (int o=0;o<64;++o) acc[o]=0.f;
    const float* xb = x + (size_t)(b*64)*NN + pix;
    const float* wT = wqkvT + gy*4096;           // [c][orel], uniform addresses
    for (int c=0;c<64;++c){
        float xv = xb[(size_t)c*NN];
        const float4* wr = (const float4*)(wT + c*64);
#pragma unroll
        for (int o4=0;o4<16;++o4){
            float4 wv = wr[o4];                  // uniform -> s_load, SGPR operands
            acc[o4*4+0] += xv*wv.x;
            acc[o4*4+1] += xv*wv.y;
            acc[o4*4+2] += xv*wv.z;
            acc[o4*4+3] += xv*wv.w;
        }
    }
    const int y = pix >> 7, xx = pix & 127;
    float* dst; size_t cstride;
    if (gy == 0){ dst = Qp + (size_t)(b*64)*NPP2 + (y+2)*HP2 + (xx+2); cstride = NPP2; }
    else { dst = ((gy==1)?Kp:Vp) + (size_t)(b*64)*NPPS + (y+2)*HPS + (xx+4); cstride = NPPS; }
    const bool dorelu = (gy < 2);
    const float* bl = bqkv + gy*64;              // uniform -> scalar
#pragma unroll
    for (int o=0;o<64;++o){
        float v = acc[o] + bl[o];
        if (dorelu) v = fmaxf(v, 0.f);
        dst[(size_t)o*cstride] = v;
    }
}

// ---------------- K2: ksum[b][h][cl*9+w] = windowed sums of Kpad ----------------------
__global__ __launch_bounds__(256) void k2_ksum(const float* __restrict__ Kp, float* __restrict__ ksum){
    const int c = blockIdx.x, b = blockIdx.y;
    const float* src = Kp + (size_t)(b*64 + c)*NPPS;
    float a[3][3];
#pragma unroll
    for (int i=0;i<3;++i)
#pragma unroll
        for (int j=0;j<3;++j) a[i][j]=0.f;
    for (int idx = threadIdx.x; idx < NPPS; idx += 256){
        int r = idx / HPS, cc = idx - r*HPS;
        float v = src[idx];
#pragma unroll
        for (int i=0;i<3;++i){
            bool fy = (unsigned)(r - 1 - i) < 128u;
#pragma unroll
            for (int j=0;j<3;++j){
                bool fx = (unsigned)(cc - 3 - j) < 128u;
                if (fy && fx) a[i][j] += v;
            }
        }
    }
    __shared__ float red[4][9];
#pragma unroll
    for (int i=0;i<3;++i)
#pragma unroll
        for (int j=0;j<3;++j){
            float v = a[i][j];
            for (int m=1;m<64;m<<=1) v += __shfl_xor(v, m, 64);
            a[i][j] = v;
        }
    int wave = threadIdx.x >> 6, lane = threadIdx.x & 63;
    if (lane == 0){
#pragma unroll
        for (int w=0;w<9;++w) red[wave][w] = a[w/3][w%3];
    }
    __syncthreads();
    if (threadIdx.x < 9){
        float s = red[0][threadIdx.x]+red[1][threadIdx.x]+red[2][threadIdx.x]+red[3][threadIdx.x];
        int h = c >> 3, cl = c & 7;
        ksum[(b*NH + h)*DD + cl*9 + threadIdx.x] = s;
    }
}

// ---------------- K3a: 5x5 cross-correlation, rolling V-row register window -----------
__global__ __launch_bounds__(256) void k3a_corr(const float* __restrict__ Kp, const float* __restrict__ Vp,
                                                float* __restrict__ Cpart){
    const int t = threadIdx.x;
    const int pair = blockIdx.x;      // cd*8+ce
    const int cd = pair >> 3, ce = pair & 7;
    const int h = blockIdx.y, b = blockIdx.z;
    const int bh = b*NH + h;
    const float* Kc = Kp + (size_t)(b*64 + h*8 + cd)*NPPS;
    const float* Vc = Vp + (size_t)(b*64 + h*8 + ce)*NPPS;
    const int x0 = (t & 31) * 4;      // image col group (4 px), contiguous across wave
    const int yb = t >> 5;            // row slice 0..7 (16 rows each)
    const int y0 = yb*16;
    float C[25];
#pragma unroll
    for (int k=0;k<25;++k) C[k]=0.f;

    float vv[5][12];                  // rolling window of padded V rows y0+it .. y0+it+4
    const float* vbase = Vc + (size_t)y0*HPS + x0;
#pragma unroll
    for (int rr=0; rr<4; ++rr){
#pragma unroll
        for (int q=0;q<3;++q){
            float4 a = *(const float4*)(vbase + rr*HPS + 4*q);
            vv[rr][4*q]=a.x; vv[rr][4*q+1]=a.y; vv[rr][4*q+2]=a.z; vv[rr][4*q+3]=a.w;
        }
    }
#pragma unroll
    for (int it=0; it<16; ++it){
        const int slot = (it+4)%5;    // static after unroll
#pragma unroll
        for (int q=0;q<3;++q){
            float4 a = *(const float4*)(vbase + (it+4)*HPS + 4*q);
            vv[slot][4*q]=a.x; vv[slot][4*q+1]=a.y; vv[slot][4*q+2]=a.z; vv[slot][4*q+3]=a.w;
        }
        float4 kk4 = *(const float4*)(Kc + (size_t)(y0+it+2)*HPS + 4 + x0);
        float kk[4] = {kk4.x, kk4.y, kk4.z, kk4.w};
#pragma unroll
        for (int dr=0; dr<5; ++dr){
            const float* vrow = vv[(it+dr)%5];
#pragma unroll
            for (int dj=0; dj<5; ++dj)
#pragma unroll
                for (int p=0; p<4; ++p)
                    C[dr*5+dj] += kk[p] * vrow[p+dj+2];
        }
    }
#pragma unroll
    for (int k=0;k<25;++k){
        float v = C[k];
        for (int m=1;m<64;m<<=1) v += __shfl_xor(v, m, 64);
        C[k] = v;
    }
    __shared__ float red[4][25];
    const int wave = t >> 6, lane = t & 63;
    if (lane == 0){
#pragma unroll
        for (int k=0;k<25;++k) red[wave][k] = C[k];
    }
    __syncthreads();
    if (t < 25){
        float s = red[0][t]+red[1][t]+red[2][t]+red[3][t];
        Cpart[((size_t)bh*64 + pair)*25 + t] = s;
    }
}

// ---------------- K3c: boundary corrections + assemble kvT2 --------------------------
__global__ __launch_bounds__(128) void k3c_kv(const float* __restrict__ Kp, const float* __restrict__ Vp,
                                              const float* __restrict__ Cpart, float* __restrict__ kvT2){
    __shared__ float Krow[2][136];   // K image rows 0 (side0) / 127 (side1)
    __shared__ float Vrow[10][136];  // V padded rows 0..4, 127..131
    __shared__ float Kcol[132][2];   // K padded cols 4 (side0) / 131 (side1), all rows
    __shared__ float Vcol[132][16];  // V padded cols 0..7, 128..135, all rows
    __shared__ float corr[100];      // [kind][side][di2][dj2]
    __shared__ float C25s[25];
    const int t = threadIdx.x;
    const int pair = blockIdx.x;
    const int cd = pair >> 3, ce = pair & 7;
    const int h = blockIdx.y, b = blockIdx.z;
    const int bh = b*NH + h;
    const float* Kc = Kp + (size_t)(b*64 + h*8 + cd)*NPPS;
    const float* Vc = Vp + (size_t)(b*64 + h*8 + ce)*NPPS;
    for (int idx=t; idx<2*136; idx+=128){
        int side = idx/136, col = idx - side*136;
        Krow[side][col] = Kc[(side?129:2)*HPS + col];
    }
    for (int idx=t; idx<10*136; idx+=128){
        int s = idx/136, col = idx - s*136;
        int row = (s<5)? s : (122+s);
        Vrow[s][col] = Vc[row*HPS + col];
    }
    for (int idx=t; idx<132*2; idx+=128){
        int row = idx>>1, side = idx&1;
        Kcol[row][side] = Kc[row*HPS + (side?131:4)];
    }
    for (int idx=t; idx<132*16; idx+=128){
        int row = idx>>4, g = idx&15;
        Vcol[row][g] = Vc[row*HPS + ((g<8)? g : (120+g))];
    }
    __syncthreads();
    if (t < 100){
        int kind = t/50, rem = t%50, side = rem/25, sh = rem%25;
        int di2 = sh/5, dj2 = sh - di2*5;
        float s = 0.f;
        if (kind == 0){
            const float* kr = &Krow[side][4];
            const float* vr = &Vrow[side*5+di2][2+dj2];
            for (int bb=0; bb<128; ++bb) s += kr[bb]*vr[bb];
        } else {
            const int g = side? (9+dj2) : (2+dj2);
            for (int a=0; a<128; ++a) s += Kcol[2+a][side]*Vcol[a+di2][g];
        }
        corr[t] = s;
    } else if (t < 125){
        C25s[t-100] = Cpart[((size_t)bh*64 + pair)*25 + (t-100)];
    }
    __syncthreads();
    if (t < 81){
        int i = t/27, j = (t/9)%3, i2 = (t/3)%3, j2 = t%3;
        int di2 = i2-i+2, dj2 = j2-j+2;
        float val = C25s[di2*5+dj2];
        int si = (i==0)?1:0;
        int sj = (j==0)?1:0;
        if (i != 1) val -= corr[si*25 + di2*5 + dj2];
        if (j != 1) val -= corr[50 + sj*25 + di2*5 + dj2];
        if (i != 1 && j != 1){
            int cj = (j==0)?127:0;
            val += Krow[si][4+cj] * Vrow[si*5+di2][2+cj+dj2];
        }
        kvT2[((size_t)bh*DD + ce*9 + i2*3 + j2)*96 + cd*12 + i*3 + j] = val;
    }
}

// ---------------- K5: fused denom (r) + numerator + fold + count-normalize ------------
__global__ __launch_bounds__(512) void k5_attn(const float* __restrict__ Qp, const float* __restrict__ kvT2,
          const float* __restrict__ ksum, float* __restrict__ folded){
    __shared__ __align__(16) float Qt[8*20*20];   // [cl][20 rows][20 cols], origin (ty0-2,tx0-2)
    __shared__ __align__(16) float rt[18*20];     // [18 rows][stride 20], origin (ty0-1,tx0-1)
    __shared__ float ks[72];
    const int t = threadIdx.x;
    const int tile = blockIdx.x;    // 8x8 tiles of 16x16
    const int h = blockIdx.y, b = blockIdx.z;
    const int ty0 = (tile >> 3)*16, tx0 = (tile & 7)*16;
    const int bh = b*NH + h;

    const float* Qb = Qp + (size_t)(b*64 + h*8)*NPP2 + (size_t)ty0*HP2 + tx0;
    for (int idx=t; idx<8*20*20; idx+=512){
        int cl = idx / 400; int rem = idx - cl*400; int r = rem/20, cc = rem - r*20;
        Qt[idx] = Qb[(size_t)cl*NPP2 + r*HP2 + cc];
    }
    if (t < 72) ks[t] = ksum[(size_t)bh*DD + t];
    __syncthreads();

    // compute rt in-block (replaces k4 + rfp round-trip). Qt's +-2 halo covers the
    // +-1 r-halo; out-of-image pixels get rt=0 (the old zero ring).
    if (t < 324){
        int rr = t/18, cc = t - rr*18;
        int py = ty0 - 1 + rr, px = tx0 - 1 + cc;
        float rv = 0.f;
        if ((unsigned)py < 128u && (unsigned)px < 128u){
            float denom = 0.f;
#pragma unroll
            for (int cl=0; cl<8; ++cl){
                const float* qb2 = &Qt[cl*400 + rr*20 + cc];
#pragma unroll
                for (int w=0; w<9; ++w)
                    denom += qb2[(w/3)*20 + (w%3)] * ks[cl*9 + w];
            }
            rv = 1.f/(denom + 1e-6f);
        }
        rt[rr*20 + cc] = rv;
    }
    __syncthreads();

    const int c  = __builtin_amdgcn_readfirstlane(t >> 6);  // wave-uniform channel
    const int l  = t & 63;
    const int pr = l >> 2;          // pixel row 0..15
    const int pc = (l & 3) * 4;     // pixel col start 0,4,8,12

    const float* kvc = kvT2 + ((size_t)bh*DD + c*9)*96;  // rows u=0..8, stride 96

    float acc[9][4];
#pragma unroll
    for (int u=0;u<9;++u)
#pragma unroll
        for (int p=0;p<4;++p) acc[u][p]=0.f;

    for (int cl=0; cl<8; ++cl){
        float qw[5][8];
        const float* qb2 = &Qt[cl*400 + pr*20 + pc];
#pragma unroll
        for (int rr=0; rr<5; ++rr){
            float4 a0 = *(const float4*)(qb2 + rr*20);
            float4 a1 = *(const float4*)(qb2 + rr*20 + 4);
            qw[rr][0]=a0.x; qw[rr][1]=a0.y; qw[rr][2]=a0.z; qw[rr][3]=a0.w;
            qw[rr][4]=a1.x; qw[rr][5]=a1.y; qw[rr][6]=a1.z; qw[rr][7]=a1.w;
        }
#pragma unroll
        for (int u=0; u<9; ++u){
            const float* kr = kvc + u*96 + cl*12;   // wave-uniform address
            float kw[9];
#pragma unroll
            for (int i=0;i<9;++i) kw[i] = kr[i];
            const int iu = u/3, ju = u - iu*3;
#pragma unroll
            for (int w=0; w<9; ++w){
                const int rr = (w/3) - iu + 2;
                const int cc = (w%3) - ju + 2;
#pragma unroll
                for (int p=0;p<4;++p)
                    acc[u][p] += qw[rr][cc+p] * kw[w];
            }
        }
    }
    float rw[3][6];
    const float* rb = &rt[pr*20 + pc];
#pragma unroll
    for (int rr=0; rr<3; ++rr)
#pragma unroll
        for (int j=0; j<6; ++j) rw[rr][j] = rb[rr*20 + j];
    float out[4];
#pragma unroll
    for (int p=0;p<4;++p) out[p]=0.f;
#pragma unroll
    for (int u=0; u<9; ++u){
        const int iu = u/3, ju = u - iu*3;
#pragma unroll
        for (int p=0;p<4;++p)
            out[p] += acc[u][p] * rw[2-iu][p+2-ju];
    }
    // count-normalize here
    const int iy = ty0 + pr;
    const float ry = 3.f - (float)(iy==0) - (float)(iy==127);
#pragma unroll
    for (int p=0;p<4;++p){
        const int ix = tx0 + pc + p;
        const float rx = 3.f - (float)(ix==0) - (float)(ix==127);
        out[p] = out[p] / (ry*rx);
    }
    float4 o4 = make_float4(out[0], out[1], out[2], out[3]);
    *(float4*)(&folded[(size_t)(b*64 + h*8 + c)*NN + (ty0+pr)*WW + tx0 + pc]) = o4;
}

// ---------------- K6: y = conv3x3(folded_norm, w_proj) + b_proj -----------------------
// Round-12 structure (8x8 tiles, grid 1024, wave-uniform oc group, single barrier) with
// conflict-free pair layout: two ci per 24-stride row -> per-phase row banks {0,24,16,8}
// tile 0..31 exactly; every ds_read_b32 is bank-perfect. Same 30.7 KB LDS.
__global__ __launch_bounds__(256) void k6_conv(const float* __restrict__ folded, const float* __restrict__ wt,
         const float* __restrict__ bproj, float* __restrict__ out){
    __shared__ float ut[32*240];    // [ci>>1][rr(10)][24: even-ci cols 0-11, odd-ci 12-23]
    const int t = threadIdx.x;
    const int tile = blockIdx.x;    // 0..255 : 16x16 grid of 8x8 tiles
    const int b = blockIdx.y;
    const int ty0 = (tile >> 4)*8, tx0 = (tile & 15)*8;

    // stage all 64 channels with halo
    for (int idx=t; idx<6400; idx+=256){
        int ci = idx / 100; int rem = idx - ci*100; int rr = rem/10, cc = rem - rr*10;
        int iy = ty0 - 1 + rr, ix = tx0 - 1 + cc;
        float v = 0.f;
        if ((unsigned)iy < 128u && (unsigned)ix < 128u)
            v = folded[(size_t)(b*64 + ci)*NN + iy*WW + ix];
        ut[(ci>>1)*240 + rr*24 + (ci&1)*12 + cc] = v;
    }
    __syncthreads();

    const int wv4 = __builtin_amdgcn_readfirstlane(t >> 6);  // wave-uniform oc group
    const int ocb = wv4*16;                                  // oc base: 0,16,32,48
    const int l  = t & 63;
    const int pr = l >> 3, pc = l & 7;                       // pixel in 8x8 tile

    float acc[16];
#pragma unroll
    for (int o=0;o<16;++o) acc[o]=0.f;

    const float* wb  = wt + ocb;                             // wave-uniform
    for (int ci=0; ci<64; ++ci){
        float u[9];
        const float* uc = &ut[(ci>>1)*240 + (ci&1)*12 + pr*24 + pc];
#pragma unroll
        for (int dy=0;dy<3;++dy)
#pragma unroll
            for (int dx=0;dx<3;++dx) u[dy*3+dx] = uc[dy*24 + dx];
#pragma unroll
        for (int w=0;w<9;++w){
            const float* kr = wb + (ci*9 + w)*64;            // wave-uniform -> s_load
            const float uv = u[w];
#pragma unroll
            for (int o=0;o<16;++o) acc[o] += kr[o]*uv;
        }
    }
    const int y = ty0 + pr, x = tx0 + pc;
    const float* bb = bproj + ocb;                           // wave-uniform
    float* dst = &out[(size_t)(b*64 + ocb)*NN + y*WW + x];
#pragma unroll
    for (int o=0;o<16;++o) dst[(size_t)o*NN] = acc[o] + bb[o];
}

extern "C" void kernel_launch(void* const* d_in, const int* in_sizes, int n_in,
                              void* d_out, int out_size, void* d_ws, size_t ws_size,
                              hipStream_t stream) {
    const float* x     = (const float*)d_in[0];
    const float* wqkv  = (const float*)d_in[1];
    const float* bqkv  = (const float*)d_in[2];
    const float* wproj = (const float*)d_in[3];
    const float* bproj = (const float*)d_in[4];
    float* out = (float*)d_out;
    float* ws  = (float*)d_ws;

    const size_t szQ2 = (size_t)BB*CC*NPP2;      // 4,460,544 floats (2-pad Q)
    const size_t szFS = (size_t)BB*CC*NPPS;      // 4,595,712 floats (132x136 K/V)
    const size_t szKV = (size_t)BB*NH*DD*96;     // 221,184 floats (kvT2)
    const size_t szKS = (size_t)BB*NH*DD;        // 2,304 floats (ksum)
    float* Qp2    = ws;
    float* Kp     = Qp2 + szQ2;
    float* Vp     = Kp + szFS;
    float* kvT2   = Vp + szFS;
    float* ksum   = kvT2 + szKV;
    float* folded = ksum + szKS;                 // B*C*N, also aliased as Cpart (k3a->k3c,
    float* wt     = folded + (size_t)BB*CC*NN;   //   consumed before k5 overwrites)
    float* wqkvT  = wt + (size_t)64*9*64;        // 3*64*64 = 12,288 floats
    float* Cpart  = folded;                      // 4*8*64*25 = 51,200 floats <= folded
    // total ~18.1M floats = ~72.4 MB of ws

    kz_pads <<<dim3(768),      256, 0, stream>>>(Qp2, Kp);
    k0_wt   <<<dim3(192),      256, 0, stream>>>(wproj, wqkv, wt, wqkvT);
    k1_qkv  <<<dim3(64, 3, 4), 256, 0, stream>>>(x, wqkvT, bqkv, Qp2, Kp, Vp);
    k2_ksum <<<dim3(64, 4),    256, 0, stream>>>(Kp, ksum);
    k3a_corr<<<dim3(64, 8, 4), 256, 0, stream>>>(Kp, Vp, Cpart);
    k3c_kv  <<<dim3(64, 8, 4), 128, 0, stream>>>(Kp, Vp, Cpart, kvT2);
    k5_attn <<<dim3(64, 8, 4), 512, 0, stream>>>(Qp2, kvT2, ksum, folded);
    k6_conv <<<dim3(256, 4),   256, 0, stream>>>(folded, wt, bproj, out);
}

// Round 15
// 336.785 us; speedup vs baseline: 1.0813x; 1.0221x over previous
//
#include <hip/hip_runtime.h>

#define BB 4
#define CC 64
#define HH 128
#define WW 128
#define NN (HH*WW)      // 16384
#define HPS 136
#define VROWS 132
#define NPPS (VROWS*HPS) // 17952 (K/V fields: 2-row pad, 4-col left pad, 136-stride)
#define HP2 132
#define NPP2 (HP2*HP2)  // 17424 (2-pad field: Q)
#define NH 8
#define DD 72
#define RTS 21          // rt row stride (coprime with 32 -> conflict-free scalar reads)

// ---------------- KZ: zero only the pad rings ----------------------------------------
__global__ __launch_bounds__(256) void kz_pads(float* __restrict__ Qp, float* __restrict__ Kp){
    const int t = threadIdx.x;
    const int c = blockIdx.x;      // 0..255 Q | 256..767 K,V
    if (c < 256){
        float* f = Qp + (size_t)c*NPP2;
        for (int idx=t; idx<4*HP2; idx+=256){
            int rs = idx / HP2, col = idx - rs*HP2;
            int row = (rs<2)? rs : (128+rs);          // 0,1,130,131
            f[row*HP2 + col] = 0.f;
        }
        for (int idx=t; idx<128*4; idx+=256){
            int row = 2 + (idx>>2), cs = idx&3;
            int col = (cs<2)? cs : (128+cs);          // 0,1,130,131
            f[row*HP2 + col] = 0.f;
        }
    } else {
        float* f = Kp + (size_t)(c-256)*NPPS;         // K then V (contiguous)
        for (int idx=t; idx<4*HPS; idx+=256){
            int rs = idx / HPS, col = idx - rs*HPS;
            int row = (rs<2)? rs : (128+rs);          // 0,1,130,131
            f[row*HPS + col] = 0.f;
        }
        for (int idx=t; idx<128*8; idx+=256){
            int row = 2 + (idx>>3), cs = idx&7;
            int col = (cs<4)? cs : (128+cs);          // 0..3, 132..135
            f[row*HPS + col] = 0.f;
        }
    }
}

// ---------------- K0: transpose w_proj -> wt[ci][w][oc]; w_qkv -> wqkvT[gy][c][orel] --
__global__ __launch_bounds__(256) void k0_wt(const float* __restrict__ wproj,
                                             const float* __restrict__ wqkv,
                                             float* __restrict__ wt, float* __restrict__ wqkvT){
    int idx = blockIdx.x*256 + threadIdx.x;      // 36864 + 12288 = 49152
    if (idx < 64*9*64){
        int oc = idx & 63;
        int w  = (idx >> 6) % 9;
        int ci = idx / 576;
        wt[idx] = wproj[(oc*64 + ci)*9 + w];
    } else if (idx < 64*9*64 + 3*64*64){
        int i2 = idx - 64*9*64;
        int orel = i2 & 63, c = (i2 >> 6) & 63, gy = i2 >> 12;
        wqkvT[i2] = wqkv[(gy*64 + orel)*64 + c];
    }
}

// ---------------- K1: qkv = x @ w_qkv^T + b ; weights via wave-uniform scalar loads ---
__global__ __launch_bounds__(256) void k1_qkv(const float* __restrict__ x,
        const float* __restrict__ wqkvT, const float* __restrict__ bqkv,
        float* __restrict__ Qp, float* __restrict__ Kp, float* __restrict__ Vp){
    const int t = threadIdx.x;
    const int gy = blockIdx.y;    // 0=q,1=k,2=v
    const int b  = blockIdx.z;
    const int pix = blockIdx.x*256 + t;
    float acc[64];
#pragma unroll
    for (int o=0;o<64;++o) acc[o]=0.f;
    const float* xb = x + (size_t)(b*64)*NN + pix;
    const float* wT = wqkvT + gy*4096;           // [c][orel], uniform addresses
    for (int c=0;c<64;++c){
        float xv = xb[(size_t)c*NN];
        const float4* wr = (const float4*)(wT + c*64);
#pragma unroll
        for (int o4=0;o4<16;++o4){
            float4 wv = wr[o4];                  // uniform -> s_load, SGPR operands
            acc[o4*4+0] += xv*wv.x;
            acc[o4*4+1] += xv*wv.y;
            acc[o4*4+2] += xv*wv.z;
            acc[o4*4+3] += xv*wv.w;
        }
    }
    const int y = pix >> 7, xx = pix & 127;
    float* dst; size_t cstride;
    if (gy == 0){ dst = Qp + (size_t)(b*64)*NPP2 + (y+2)*HP2 + (xx+2); cstride = NPP2; }
    else { dst = ((gy==1)?Kp:Vp) + (size_t)(b*64)*NPPS + (y+2)*HPS + (xx+4); cstride = NPPS; }
    const bool dorelu = (gy < 2);
    const float* bl = bqkv + gy*64;              // uniform -> scalar
#pragma unroll
    for (int o=0;o<64;++o){
        float v = acc[o] + bl[o];
        if (dorelu) v = fmaxf(v, 0.f);
        dst[(size_t)o*cstride] = v;
    }
}

// ---------------- K2: ksum[b][h][cl*9+w] = windowed sums of Kpad ----------------------
__global__ __launch_bounds__(256) void k2_ksum(const float* __restrict__ Kp, float* __restrict__ ksum){
    const int c = blockIdx.x, b = blockIdx.y;
    const float* src = Kp + (size_t)(b*64 + c)*NPPS;
    float a[3][3];
#pragma unroll
    for (int i=0;i<3;++i)
#pragma unroll
        for (int j=0;j<3;++j) a[i][j]=0.f;
    for (int idx = threadIdx.x; idx < NPPS; idx += 256){
        int r = idx / HPS, cc = idx - r*HPS;
        float v = src[idx];
#pragma unroll
        for (int i=0;i<3;++i){
            bool fy = (unsigned)(r - 1 - i) < 128u;
#pragma unroll
            for (int j=0;j<3;++j){
                bool fx = (unsigned)(cc - 3 - j) < 128u;
                if (fy && fx) a[i][j] += v;
            }
        }
    }
    __shared__ float red[4][9];
#pragma unroll
    for (int i=0;i<3;++i)
#pragma unroll
        for (int j=0;j<3;++j){
            float v = a[i][j];
            for (int m=1;m<64;m<<=1) v += __shfl_xor(v, m, 64);
            a[i][j] = v;
        }
    int wave = threadIdx.x >> 6, lane = threadIdx.x & 63;
    if (lane == 0){
#pragma unroll
        for (int w=0;w<9;++w) red[wave][w] = a[w/3][w%3];
    }
    __syncthreads();
    if (threadIdx.x < 9){
        float s = red[0][threadIdx.x]+red[1][threadIdx.x]+red[2][threadIdx.x]+red[3][threadIdx.x];
        int h = c >> 3, cl = c & 7;
        ksum[(b*NH + h)*DD + cl*9 + threadIdx.x] = s;
    }
}

// ---------------- K3a: 5x5 cross-correlation, rolling V-row register window -----------
__global__ __launch_bounds__(256) void k3a_corr(const float* __restrict__ Kp, const float* __restrict__ Vp,
                                                float* __restrict__ Cpart){
    const int t = threadIdx.x;
    const int pair = blockIdx.x;      // cd*8+ce
    const int cd = pair >> 3, ce = pair & 7;
    const int h = blockIdx.y, b = blockIdx.z;
    const int bh = b*NH + h;
    const float* Kc = Kp + (size_t)(b*64 + h*8 + cd)*NPPS;
    const float* Vc = Vp + (size_t)(b*64 + h*8 + ce)*NPPS;
    const int x0 = (t & 31) * 4;      // image col group (4 px), contiguous across wave
    const int yb = t >> 5;            // row slice 0..7 (16 rows each)
    const int y0 = yb*16;
    float C[25];
#pragma unroll
    for (int k=0;k<25;++k) C[k]=0.f;

    float vv[5][12];                  // rolling window of padded V rows y0+it .. y0+it+4
    const float* vbase = Vc + (size_t)y0*HPS + x0;
#pragma unroll
    for (int rr=0; rr<4; ++rr){
#pragma unroll
        for (int q=0;q<3;++q){
            float4 a = *(const float4*)(vbase + rr*HPS + 4*q);
            vv[rr][4*q]=a.x; vv[rr][4*q+1]=a.y; vv[rr][4*q+2]=a.z; vv[rr][4*q+3]=a.w;
        }
    }
#pragma unroll
    for (int it=0; it<16; ++it){
        const int slot = (it+4)%5;    // static after unroll
#pragma unroll
        for (int q=0;q<3;++q){
            float4 a = *(const float4*)(vbase + (it+4)*HPS + 4*q);
            vv[slot][4*q]=a.x; vv[slot][4*q+1]=a.y; vv[slot][4*q+2]=a.z; vv[slot][4*q+3]=a.w;
        }
        float4 kk4 = *(const float4*)(Kc + (size_t)(y0+it+2)*HPS + 4 + x0);
        float kk[4] = {kk4.x, kk4.y, kk4.z, kk4.w};
#pragma unroll
        for (int dr=0; dr<5; ++dr){
            const float* vrow = vv[(it+dr)%5];
#pragma unroll
            for (int dj=0; dj<5; ++dj)
#pragma unroll
                for (int p=0; p<4; ++p)
                    C[dr*5+dj] += kk[p] * vrow[p+dj+2];
        }
    }
#pragma unroll
    for (int k=0;k<25;++k){
        float v = C[k];
        for (int m=1;m<64;m<<=1) v += __shfl_xor(v, m, 64);
        C[k] = v;
    }
    __shared__ float red[4][25];
    const int wave = t >> 6, lane = t & 63;
    if (lane == 0){
#pragma unroll
        for (int k=0;k<25;++k) red[wave][k] = C[k];
    }
    __syncthreads();
    if (t < 25){
        float s = red[0][t]+red[1][t]+red[2][t]+red[3][t];
        Cpart[((size_t)bh*64 + pair)*25 + t] = s;
    }
}

// ---------------- K3c: boundary corrections + assemble kvT2 --------------------------
__global__ __launch_bounds__(128) void k3c_kv(const float* __restrict__ Kp, const float* __restrict__ Vp,
                                              const float* __restrict__ Cpart, float* __restrict__ kvT2){
    __shared__ float Krow[2][136];   // K image rows 0 (side0) / 127 (side1)
    __shared__ float Vrow[10][136];  // V padded rows 0..4, 127..131
    __shared__ float Kcol[132][2];   // K padded cols 4 (side0) / 131 (side1), all rows
    __shared__ float Vcol[132][16];  // V padded cols 0..7, 128..135, all rows
    __shared__ float corr[100];      // [kind][side][di2][dj2]
    __shared__ float C25s[25];
    const int t = threadIdx.x;
    const int pair = blockIdx.x;
    const int cd = pair >> 3, ce = pair & 7;
    const int h = blockIdx.y, b = blockIdx.z;
    const int bh = b*NH + h;
    const float* Kc = Kp + (size_t)(b*64 + h*8 + cd)*NPPS;
    const float* Vc = Vp + (size_t)(b*64 + h*8 + ce)*NPPS;
    for (int idx=t; idx<2*136; idx+=128){
        int side = idx/136, col = idx - side*136;
        Krow[side][col] = Kc[(side?129:2)*HPS + col];
    }
    for (int idx=t; idx<10*136; idx+=128){
        int s = idx/136, col = idx - s*136;
        int row = (s<5)? s : (122+s);
        Vrow[s][col] = Vc[row*HPS + col];
    }
    for (int idx=t; idx<132*2; idx+=128){
        int row = idx>>1, side = idx&1;
        Kcol[row][side] = Kc[row*HPS + (side?131:4)];
    }
    for (int idx=t; idx<132*16; idx+=128){
        int row = idx>>4, g = idx&15;
        Vcol[row][g] = Vc[row*HPS + ((g<8)? g : (120+g))];
    }
    __syncthreads();
    if (t < 100){
        int kind = t/50, rem = t%50, side = rem/25, sh = rem%25;
        int di2 = sh/5, dj2 = sh - di2*5;
        float s = 0.f;
        if (kind == 0){
            const float* kr = &Krow[side][4];
            const float* vr = &Vrow[side*5+di2][2+dj2];
            for (int bb=0; bb<128; ++bb) s += kr[bb]*vr[bb];
        } else {
            const int g = side? (9+dj2) : (2+dj2);
            for (int a=0; a<128; ++a) s += Kcol[2+a][side]*Vcol[a+di2][g];
        }
        corr[t] = s;
    } else if (t < 125){
        C25s[t-100] = Cpart[((size_t)bh*64 + pair)*25 + (t-100)];
    }
    __syncthreads();
    if (t < 81){
        int i = t/27, j = (t/9)%3, i2 = (t/3)%3, j2 = t%3;
        int di2 = i2-i+2, dj2 = j2-j+2;
        float val = C25s[di2*5+dj2];
        int si = (i==0)?1:0;
        int sj = (j==0)?1:0;
        if (i != 1) val -= corr[si*25 + di2*5 + dj2];
        if (j != 1) val -= corr[50 + sj*25 + di2*5 + dj2];
        if (i != 1 && j != 1){
            int cj = (j==0)?127:0;
            val += Krow[si][4+cj] * Vrow[si*5+di2][2+cj+dj2];
        }
        kvT2[((size_t)bh*DD + ce*9 + i2*3 + j2)*96 + cd*12 + i*3 + j] = val;
    }
}

// ---------------- K5: fused denom (r) + numerator + fold + count-normalize ------------
// Lane map pr=l&15, pc=(l>>4)*4: 8-lane b128 groups hit bases {0,20,8,28,16,4,24,12}
// mod 32 — a perfect bank tile at any serving granularity (fixes the 26M conflicts).
__global__ __launch_bounds__(512) void k5_attn(const float* __restrict__ Qp, const float* __restrict__ kvT2,
          const float* __restrict__ ksum, float* __restrict__ folded){
    __shared__ __align__(16) float Qt[8*20*20];   // [cl][20 rows][20 cols], origin (ty0-2,tx0-2)
    __shared__ __align__(16) float rt[18*RTS];    // [18 rows][stride 21], origin (ty0-1,tx0-1)
    __shared__ float ks[72];
    const int t = threadIdx.x;
    const int tile = blockIdx.x;    // 8x8 tiles of 16x16
    const int h = blockIdx.y, b = blockIdx.z;
    const int ty0 = (tile >> 3)*16, tx0 = (tile & 7)*16;
    const int bh = b*NH + h;

    const float* Qb = Qp + (size_t)(b*64 + h*8)*NPP2 + (size_t)ty0*HP2 + tx0;
    for (int idx=t; idx<8*20*20; idx+=512){
        int cl = idx / 400; int rem = idx - cl*400; int r = rem/20, cc = rem - r*20;
        Qt[idx] = Qb[(size_t)cl*NPP2 + r*HP2 + cc];
    }
    if (t < 72) ks[t] = ksum[(size_t)bh*DD + t];
    __syncthreads();

    // compute rt in-block; Qt's +-2 halo covers the +-1 r-halo; out-of-image -> 0.
    if (t < 324){
        int rr = t/18, cc = t - rr*18;
        int py = ty0 - 1 + rr, px = tx0 - 1 + cc;
        float rv = 0.f;
        if ((unsigned)py < 128u && (unsigned)px < 128u){
            float denom = 0.f;
#pragma unroll
            for (int cl=0; cl<8; ++cl){
                const float* qb2 = &Qt[cl*400 + rr*20 + cc];
#pragma unroll
                for (int w=0; w<9; ++w)
                    denom += qb2[(w/3)*20 + (w%3)] * ks[cl*9 + w];
            }
            rv = 1.f/(denom + 1e-6f);
        }
        rt[rr*RTS + cc] = rv;
    }
    __syncthreads();

    const int c  = __builtin_amdgcn_readfirstlane(t >> 6);  // wave-uniform channel
    const int l  = t & 63;
    const int pr = l & 15;          // pixel row 0..15 (bank-perfect b128 groups)
    const int pc = (l >> 4) * 4;    // pixel col start 0,4,8,12

    const float* kvc = kvT2 + ((size_t)bh*DD + c*9)*96;  // rows u=0..8, stride 96

    float acc[9][4];
#pragma unroll
    for (int u=0;u<9;++u)
#pragma unroll
        for (int p=0;p<4;++p) acc[u][p]=0.f;

    for (int cl=0; cl<8; ++cl){
        float qw[5][8];
        const float* qb2 = &Qt[cl*400 + pr*20 + pc];
#pragma unroll
        for (int rr=0; rr<5; ++rr){
            float4 a0 = *(const float4*)(qb2 + rr*20);
            float4 a1 = *(const float4*)(qb2 + rr*20 + 4);
            qw[rr][0]=a0.x; qw[rr][1]=a0.y; qw[rr][2]=a0.z; qw[rr][3]=a0.w;
            qw[rr][4]=a1.x; qw[rr][5]=a1.y; qw[rr][6]=a1.z; qw[rr][7]=a1.w;
        }
#pragma unroll
        for (int u=0; u<9; ++u){
            const float* kr = kvc + u*96 + cl*12;   // wave-uniform address
            float kw[9];
#pragma unroll
            for (int i=0;i<9;++i) kw[i] = kr[i];
            const int iu = u/3, ju = u - iu*3;
#pragma unroll
            for (int w=0; w<9; ++w){
                const int rr = (w/3) - iu + 2;
                const int cc = (w%3) - ju + 2;
#pragma unroll
                for (int p=0;p<4;++p)
                    acc[u][p] += qw[rr][cc+p] * kw[w];
            }
        }
    }
    float rw[3][6];
    const float* rb = &rt[pr*RTS + pc];
#pragma unroll
    for (int rr=0; rr<3; ++rr)
#pragma unroll
        for (int j=0; j<6; ++j) rw[rr][j] = rb[rr*RTS + j];
    float out[4];
#pragma unroll
    for (int p=0;p<4;++p) out[p]=0.f;
#pragma unroll
    for (int u=0; u<9; ++u){
        const int iu = u/3, ju = u - iu*3;
#pragma unroll
        for (int p=0;p<4;++p)
            out[p] += acc[u][p] * rw[2-iu][p+2-ju];
    }
    // count-normalize here
    const int iy = ty0 + pr;
    const float ry = 3.f - (float)(iy==0) - (float)(iy==127);
#pragma unroll
    for (int p=0;p<4;++p){
        const int ix = tx0 + pc + p;
        const float rx = 3.f - (float)(ix==0) - (float)(ix==127);
        out[p] = out[p] / (ry*rx);
    }
    float4 o4 = make_float4(out[0], out[1], out[2], out[3]);
    *(float4*)(&folded[(size_t)(b*64 + h*8 + c)*NN + (ty0+pr)*WW + tx0 + pc]) = o4;
}

// ---------------- K6: y = conv3x3(folded_norm, w_proj) + b_proj -----------------------
__global__ __launch_bounds__(256) void k6_conv(const float* __restrict__ folded, const float* __restrict__ wt,
         const float* __restrict__ bproj, float* __restrict__ out){
    __shared__ float ut[32*240];    // [ci>>1][rr(10)][24: even-ci cols 0-11, odd-ci 12-23]
    const int t = threadIdx.x;
    const int tile = blockIdx.x;    // 0..255 : 16x16 grid of 8x8 tiles
    const int b = blockIdx.y;
    const int ty0 = (tile >> 4)*8, tx0 = (tile & 15)*8;

    // stage all 64 channels with halo
    for (int idx=t; idx<6400; idx+=256){
        int ci = idx / 100; int rem = idx - ci*100; int rr = rem/10, cc = rem - rr*10;
        int iy = ty0 - 1 + rr, ix = tx0 - 1 + cc;
        float v = 0.f;
        if ((unsigned)iy < 128u && (unsigned)ix < 128u)
            v = folded[(size_t)(b*64 + ci)*NN + iy*WW + ix];
        ut[(ci>>1)*240 + rr*24 + (ci&1)*12 + cc] = v;
    }
    __syncthreads();

    const int wv4 = __builtin_amdgcn_readfirstlane(t >> 6);  // wave-uniform oc group
    const int ocb = wv4*16;                                  // oc base: 0,16,32,48
    const int l  = t & 63;
    const int pr = l >> 3, pc = l & 7;                       // pixel in 8x8 tile

    float acc[16];
#pragma unroll
    for (int o=0;o<16;++o) acc[o]=0.f;

    const float* wb  = wt + ocb;                             // wave-uniform
    for (int ci=0; ci<64; ++ci){
        float u[9];
        const float* uc = &ut[(ci>>1)*240 + (ci&1)*12 + pr*24 + pc];
#pragma unroll
        for (int dy=0;dy<3;++dy)
#pragma unroll
            for (int dx=0;dx<3;++dx) u[dy*3+dx] = uc[dy*24 + dx];
#pragma unroll
        for (int w=0;w<9;++w){
            const float* kr = wb + (ci*9 + w)*64;            // wave-uniform -> s_load
            const float uv = u[w];
#pragma unroll
            for (int o=0;o<16;++o) acc[o] += kr[o]*uv;
        }
    }
    const int y = ty0 + pr, x = tx0 + pc;
    const float* bb = bproj + ocb;                           // wave-uniform
    float* dst = &out[(size_t)(b*64 + ocb)*NN + y*WW + x];
#pragma unroll
    for (int o=0;o<16;++o) dst[(size_t)o*NN] = acc[o] + bb[o];
}

extern "C" void kernel_launch(void* const* d_in, const int* in_sizes, int n_in,
                              void* d_out, int out_size, void* d_ws, size_t ws_size,
                              hipStream_t stream) {
    const float* x     = (const float*)d_in[0];
    const float* wqkv  = (const float*)d_in[1];
    const float* bqkv  = (const float*)d_in[2];
    const float* wproj = (const float*)d_in[3];
    const float* bproj = (const float*)d_in[4];
    float* out = (float*)d_out;
    float* ws  = (float*)d_ws;

    const size_t szQ2 = (size_t)BB*CC*NPP2;      // 4,460,544 floats (2-pad Q)
    const size_t szFS = (size_t)BB*CC*NPPS;      // 4,595,712 floats (132x136 K/V)
    const size_t szKV = (size_t)BB*NH*DD*96;     // 221,184 floats (kvT2)
    const size_t szKS = (size_t)BB*NH*DD;        // 2,304 floats (ksum)
    float* Qp2    = ws;
    float* Kp     = Qp2 + szQ2;
    float* Vp     = Kp + szFS;
    float* kvT2   = Vp + szFS;
    float* ksum   = kvT2 + szKV;
    float* folded = ksum + szKS;                 // B*C*N, also aliased as Cpart (k3a->k3c,
    float* wt     = folded + (size_t)BB*CC*NN;   //   consumed before k5 overwrites)
    float* wqkvT  = wt + (size_t)64*9*64;        // 3*64*64 = 12,288 floats
    float* Cpart  = folded;                      // 4*8*64*25 = 51,200 floats <= folded
    // total ~18.1M floats = ~72.4 MB of ws

    kz_pads <<<dim3(768),      256, 0, stream>>>(Qp2, Kp);
    k0_wt   <<<dim3(192),      256, 0, stream>>>(wproj, wqkv, wt, wqkvT);
    k1_qkv  <<<dim3(64, 3, 4), 256, 0, stream>>>(x, wqkvT, bqkv, Qp2, Kp, Vp);
    k2_ksum <<<dim3(64, 4),    256, 0, stream>>>(Kp, ksum);
    k3a_corr<<<dim3(64, 8, 4), 256, 0, stream>>>(Kp, Vp, Cpart);
    k3c_kv  <<<dim3(64, 8, 4), 128, 0, stream>>>(Kp, Vp, Cpart, kvT2);
    k5_attn <<<dim3(64, 8, 4), 512, 0, stream>>>(Qp2, kvT2, ksum, folded);
    k6_conv <<<dim3(256, 4),   256, 0, stream>>>(folded, wt, bproj, out);
}